// Round 2
// baseline (174.445 us; speedup 1.0000x reference)
//
#include <hip/hip_runtime.h>

#define LR 0.01f
#define NSTEPS 100

// Native 4-float vector: __builtin_nontemporal_load/store require a real
// vector type, not HIP's struct-wrapped float4.
typedef float f4 __attribute__((ext_vector_type(4)));

// u_{k+1} = a*u_k + c with a = 1-2*LR*q, c = -LR*p, per element of (B,4),
// q/p = cols 12..15 of the (B,16) Q/p arrays.
//
// R0-R3 lesson: reading 16 B at stride 64 B (one sector per DRAM burst)
// plateaus at ~1.3 TB/s fetch regardless of batching/occupancy — the address
// pattern is the ceiling. Fix: STREAM Q and p fully contiguously (64 B/lane,
// full-burst efficiency), then redistribute in-register with a fixed wave
// permutation. 160 MB of sequential traffic -> ~27 us @ 6 TB/s.
//
// R4/R5: all global traffic is single-touch streaming (zero reuse) -> mark
// loads/stores nontemporal so the 144 MB read stream doesn't churn L2/LLC.
__global__ __launch_bounds__(256) void diffmpc_kernel(
    const f4* __restrict__ Qv,
    const f4* __restrict__ Pv,
    const f4* __restrict__ Uv,
    f4* __restrict__ Ov)
{
    const int wave = (int)((blockIdx.x * blockDim.x + threadIdx.x) >> 6);
    const int lane = (int)(threadIdx.x & 63);
    const long b0   = (long)wave << 6;   // first row of this wave's 64-row tile
    const long base = b0 * 4;            // tile start, in float4 units

    // Fully-coalesced streaming: 256 consecutive float4s = rows b0..b0+63 of Q.
    f4 q[4], pr[4];
#pragma unroll
    for (int j = 0; j < 4; ++j) q[j]  = __builtin_nontemporal_load(&Qv[base + j * 64 + lane]);
#pragma unroll
    for (int j = 0; j < 4; ++j) pr[j] = __builtin_nontemporal_load(&Pv[base + j * 64 + lane]);
    f4 u = __builtin_nontemporal_load(&Uv[b0 + lane]);  // (B,4) rows: natively coalesced

    // Lane L needs tile-local float4 index 4L+3 (cols 12..15 of row b0+L),
    // which sits in register j = L>>4 of lane (4L+3)&63.
    const int src  = (4 * lane + 3) & 63;
    const int jsel = lane >> 4;
    f4 q4, p4;
#pragma unroll
    for (int j = 0; j < 4; ++j) {
        f4 tq, tp;
        tq.x = __shfl(q[j].x,  src); tq.y = __shfl(q[j].y,  src);
        tq.z = __shfl(q[j].z,  src); tq.w = __shfl(q[j].w,  src);
        tp.x = __shfl(pr[j].x, src); tp.y = __shfl(pr[j].y, src);
        tp.z = __shfl(pr[j].z, src); tp.w = __shfl(pr[j].w, src);
        if (jsel == j) { q4 = tq; p4 = tp; }
    }

    const float ax = fmaf(-2.0f * LR, q4.x, 1.0f);
    const float ay = fmaf(-2.0f * LR, q4.y, 1.0f);
    const float az = fmaf(-2.0f * LR, q4.z, 1.0f);
    const float aw = fmaf(-2.0f * LR, q4.w, 1.0f);
    const float cx = -LR * p4.x;
    const float cy = -LR * p4.y;
    const float cz = -LR * p4.z;
    const float cw = -LR * p4.w;

#pragma unroll 10
    for (int i = 0; i < NSTEPS; ++i) {
        u.x = fmaf(ax, u.x, cx);
        u.y = fmaf(ay, u.y, cy);
        u.z = fmaf(az, u.z, cz);
        u.w = fmaf(aw, u.w, cw);
    }

    __builtin_nontemporal_store(u, &Ov[b0 + lane]);
}

extern "C" void kernel_launch(void* const* d_in, const int* in_sizes, int n_in,
                              void* d_out, int out_size, void* d_ws, size_t ws_size,
                              hipStream_t stream) {
    // Inputs: x_init (B,12) [UNUSED], Q (B,16), p (B,16), u_init (B,4)
    const f4* Qv = (const f4*)d_in[1];
    const f4* Pv = (const f4*)d_in[2];
    const f4* Uv = (const f4*)d_in[3];
    f4* Ov = (f4*)d_out;

    const int B = in_sizes[3] / 4;   // 1,048,576 rows
    const int waves = B / 64;        // 16,384 waves (exact)
    const int block = 256;           // 4 waves/block
    const int grid = waves / 4;      // 4,096 blocks

    diffmpc_kernel<<<grid, block, 0, stream>>>(Qv, Pv, Uv, Ov);
}